// Round 4
// baseline (1454.723 us; speedup 1.0000x reference)
//
#include <hip/hip_runtime.h>
#include <stdint.h>

// bf16 flash-attention forward, causal, B=2 H=16 T=4096 D=128, fp32 in/out.
// S^T = K*Q^T (q on lane&31 for softmax), O^T = V^T*P^T (alpha per-lane).
// R4: back to 256-thr/BQ=128 (R3's 512-thr + launch_bounds(512,4) spilled:
// reg demand is ~150/wave, hard 3 waves/EU ceiling). New: (a) cheap packed
// bf16 conversion (add+v_perm, 1.5 op/elem vs 5), (b) P C-layout -> B-layout
// transform via 4x 64-bit shfl_xor(32) in registers instead of LDS round
// trip -> LDS 54.3 -> 35.8 KB -> 3 blocks/CU (12 waves/CU).

typedef __bf16 bf16x8 __attribute__((ext_vector_type(8)));
typedef float f32x16 __attribute__((ext_vector_type(16)));
typedef unsigned short u16x8 __attribute__((ext_vector_type(8)));
typedef unsigned int u32x4 __attribute__((ext_vector_type(4)));
typedef unsigned int u32x2 __attribute__((ext_vector_type(2)));

#define T_SEQ 4096
#define D_HEAD 128
#define BQ 128          // q rows per block (4 waves x 32)
#define BK 64           // kv rows per tile
#define KSTR 136        // K_lds row stride in shorts (128 + 8 pad)
#define VSTR 72         // Vt_lds row stride in shorts (64 + 8 pad)

// pack two f32 -> packed bf16x2 (round-half-up: +0x8000 then take hi16).
// 3 VALU ops per 2 elements vs ~10 for manual RNE.
__device__ __forceinline__ unsigned int pack_bf2(float a, float b) {
    unsigned int ua = __builtin_bit_cast(unsigned int, a) + 0x8000u;
    unsigned int ub = __builtin_bit_cast(unsigned int, b) + 0x8000u;
    return __builtin_amdgcn_perm(ub, ua, 0x07060302);  // [ub.hi16 | ua.hi16]
}

__global__ __launch_bounds__(256, 3) void fa_fwd(
    const float* __restrict__ Qg, const float* __restrict__ Kg,
    const float* __restrict__ Vg, float* __restrict__ Og)
{
    __shared__ unsigned short K_lds[BK * KSTR];        // K[kv][d]     17408 B
    __shared__ unsigned short Vt_lds[D_HEAD * VSTR];   // V^T[d][kv]   18432 B

    const int tid  = threadIdx.x;
    const int lane = tid & 63;
    const int r    = lane & 31;     // n-index within MFMA tiles (= q offset)
    const int h    = lane >> 5;     // half-wave
    const int w    = tid >> 6;      // wave 0..3

    const int qt = (int)(gridDim.x - 1 - blockIdx.x); // big tiles first
    const int bh = blockIdx.y;
    const int q0 = qt * BQ;

    const float* Qb = Qg + (size_t)bh * T_SEQ * D_HEAD;
    const float* Kb = Kg + (size_t)bh * T_SEQ * D_HEAD;
    const float* Vb = Vg + (size_t)bh * T_SEQ * D_HEAD;
    float*       Ob = Og + (size_t)bh * T_SEQ * D_HEAD;

    const int qw      = q0 + 32 * w;     // wave's first q row
    const int q_lane  = qw + r;          // this lane's q column (S^T layout)
    const int qw_last = qw + 31;

    // ---- Q fragments (B-operand: B[k=d][n=q]), pre-scaled by 1/sqrt(D)*log2(e)
    const float qscale = 0.08838834764831845f * 1.4426950408889634f;
    bf16x8 qf[8];
#pragma unroll
    for (int c = 0; c < 8; ++c) {
        const float* src = Qb + (size_t)q_lane * D_HEAD + c * 16 + h * 8;
        float4 f0 = *(const float4*)(src);
        float4 f1 = *(const float4*)(src + 4);
        u32x4 u;
        u[0] = pack_bf2(f0.x * qscale, f0.y * qscale);
        u[1] = pack_bf2(f0.z * qscale, f0.w * qscale);
        u[2] = pack_bf2(f1.x * qscale, f1.y * qscale);
        u[3] = pack_bf2(f1.z * qscale, f1.w * qscale);
        qf[c] = __builtin_bit_cast(bf16x8, u);
    }

    f32x16 o[4];                      // O^T accum, 4 d-blocks of 32
#pragma unroll
    for (int mt = 0; mt < 4; ++mt) o[mt] = (f32x16)0.0f;
    float m_run = -1e30f, l_run = 0.0f;

    const int ntiles = 2 * qt + 2;
    for (int kt = 0; kt < ntiles; ++kt) {
        const int kbase = kt * BK;
        __syncthreads();   // previous tile's LDS reads done before restage

        // ---- stage K tile: K_lds[row][d], coalesced float4 reads
        {
            const int row = tid >> 5;            // 0..7
            const int d0  = (tid & 31) * 4;
#pragma unroll
            for (int p = 0; p < 8; ++p) {
                const int rr = p * 8 + row;
                float4 kf = *(const float4*)(Kb + (size_t)(kbase + rr) * D_HEAD + d0);
                u32x2 u;
                u[0] = pack_bf2(kf.x, kf.y);
                u[1] = pack_bf2(kf.z, kf.w);
                *(u32x2*)&K_lds[rr * KSTR + d0] = u;
            }
        }
        // ---- stage V tile transposed: Vt_lds[d][kv], coalesced scalar reads
        {
            const int d  = tid & 127;
            const int hh = tid >> 7;             // 0,1
#pragma unroll
            for (int p = 0; p < 8; ++p) {
                const int kv0 = p * 8 + hh * 4;
                const float* vs = Vb + (size_t)(kbase + kv0) * D_HEAD + d;
                u32x2 u;
                u[0] = pack_bf2(vs[0], vs[D_HEAD]);
                u[1] = pack_bf2(vs[2 * D_HEAD], vs[3 * D_HEAD]);
                *(u32x2*)&Vt_lds[d * VSTR + kv0] = u;
            }
        }
        __syncthreads();

        if (kbase > qw_last) continue;   // wave-uniform skip; barriers stay aligned

        // ---- S^T = K * Q^T : two 32-kv m-tiles
        f32x16 s[2];
        s[0] = (f32x16)0.0f; s[1] = (f32x16)0.0f;
#pragma unroll
        for (int t = 0; t < 2; ++t) {
#pragma unroll
            for (int c = 0; c < 8; ++c) {
                u16x8 raw = *(const u16x8*)&K_lds[(t * 32 + r) * KSTR + c * 16 + h * 8];
                bf16x8 a = __builtin_bit_cast(bf16x8, raw);
                s[t] = __builtin_amdgcn_mfma_f32_32x32x16_bf16(a, qf[c], s[t], 0, 0, 0);
            }
        }

        // ---- causal mask: needed iff tile contains kv beyond the wave's FIRST q
        if (kbase + BK - 1 > qw) {
#pragma unroll
            for (int t = 0; t < 2; ++t)
#pragma unroll
                for (int g = 0; g < 16; ++g) {
                    int kv = kbase + t * 32 + (g & 3) + 8 * (g >> 2) + 4 * h;
                    if (kv > q_lane) s[t][g] = -1e30f;
                }
        }

        // ---- online softmax (per q = lane&31; combine the two half-waves)
        float mloc = -1e30f;
#pragma unroll
        for (int t = 0; t < 2; ++t)
#pragma unroll
            for (int g = 0; g < 16; ++g) mloc = fmaxf(mloc, s[t][g]);
        mloc = fmaxf(mloc, __shfl_xor(mloc, 32, 64));
        const float m_new = fmaxf(m_run, mloc);
        const float alpha = __builtin_amdgcn_exp2f(m_run - m_new);
        float rsum = 0.0f;
#pragma unroll
        for (int t = 0; t < 2; ++t)
#pragma unroll
            for (int g = 0; g < 16; ++g) {
                float p = __builtin_amdgcn_exp2f(s[t][g] - m_new);
                s[t][g] = p;
                rsum += p;
            }
        rsum += __shfl_xor(rsum, 32, 64);
        l_run = l_run * alpha + rsum;
        m_run = m_new;
#pragma unroll
        for (int mt = 0; mt < 4; ++mt)
#pragma unroll
            for (int g = 0; g < 16; ++g) o[mt][g] *= alpha;

        // ---- pack P quads: quad e=4t+g2 of lane (r,h) holds kv=8e+4h+(0..3)
        unsigned int pq_lo[8], pq_hi[8];
#pragma unroll
        for (int e = 0; e < 8; ++e) {
            const int t = e >> 2, g2 = e & 3;
            pq_lo[e] = pack_bf2(s[t][g2 * 4 + 0], s[t][g2 * 4 + 1]);
            pq_hi[e] = pack_bf2(s[t][g2 * 4 + 2], s[t][g2 * 4 + 3]);
        }

        // ---- C-layout -> B-layout transform in registers:
        // pf[c] elem j = P[kv=16c+8h+j][q=r]; j0..3 from half-wave 0's quad
        // (2c+h), j4..7 from half-wave 1's quad (2c+h). Exchange via
        // shfl_xor(32): each lane SENDS quad (2c + (h^1)) (what partner needs)
        // and RECEIVES partner's quad (2c+h).
        bf16x8 pf[4];
#pragma unroll
        for (int c = 0; c < 4; ++c) {
            const unsigned int own_lo = h ? pq_lo[2 * c + 1] : pq_lo[2 * c];
            const unsigned int own_hi = h ? pq_hi[2 * c + 1] : pq_hi[2 * c];
            const unsigned int snd_lo = h ? pq_lo[2 * c] : pq_lo[2 * c + 1];
            const unsigned int snd_hi = h ? pq_hi[2 * c] : pq_hi[2 * c + 1];
            const unsigned int oth_lo = (unsigned int)__shfl_xor((int)snd_lo, 32, 64);
            const unsigned int oth_hi = (unsigned int)__shfl_xor((int)snd_hi, 32, 64);
            u32x4 u;
            u[0] = h ? oth_lo : own_lo;   // j0..1
            u[1] = h ? oth_hi : own_hi;   // j2..3
            u[2] = h ? own_lo : oth_lo;   // j4..5
            u[3] = h ? own_hi : oth_hi;   // j6..7
            pf[c] = __builtin_bit_cast(bf16x8, u);
        }

        // ---- O^T += V^T * P^T
#pragma unroll
        for (int mt = 0; mt < 4; ++mt) {
#pragma unroll
            for (int c = 0; c < 4; ++c) {
                u16x8 raw = *(const u16x8*)&Vt_lds[(mt * 32 + r) * VSTR + c * 16 + h * 8];
                bf16x8 a = __builtin_bit_cast(bf16x8, raw);
                o[mt] = __builtin_amdgcn_mfma_f32_32x32x16_bf16(a, pf[c], o[mt], 0, 0, 0);
            }
        }
    }

    // ---- epilogue: O[q][d] = O^T / l  (float4 stores, lane's q row fixed)
    const float inv = 1.0f / l_run;
#pragma unroll
    for (int mt = 0; mt < 4; ++mt)
#pragma unroll
        for (int g4 = 0; g4 < 4; ++g4) {
            float4 vv;
            vv.x = o[mt][g4 * 4 + 0] * inv;
            vv.y = o[mt][g4 * 4 + 1] * inv;
            vv.z = o[mt][g4 * 4 + 2] * inv;
            vv.w = o[mt][g4 * 4 + 3] * inv;
            const int dd = mt * 32 + g4 * 8 + h * 4;
            *(float4*)(Ob + (size_t)q_lane * D_HEAD + dd) = vv;
        }
}

extern "C" void kernel_launch(void* const* d_in, const int* in_sizes, int n_in,
                              void* d_out, int out_size, void* d_ws, size_t ws_size,
                              hipStream_t stream) {
    const float* Q = (const float*)d_in[0];
    const float* K = (const float*)d_in[1];
    const float* V = (const float*)d_in[2];
    float* O = (float*)d_out;
    const int BH = in_sizes[0] / (T_SEQ * D_HEAD);   // 32
    dim3 grid(T_SEQ / BQ, BH, 1);
    fa_fwd<<<grid, 256, 0, stream>>>(Q, K, V, O);
}

// Round 5
// 506.427 us; speedup vs baseline: 2.8725x; 2.8725x over previous
//
#include <hip/hip_runtime.h>
#include <stdint.h>

// bf16 flash-attention forward, causal, B=2 H=16 T=4096 D=128, fp32 in/out.
// S^T = K*Q^T (q on lane&31 for softmax), O^T = V^T*P^T (alpha per-lane).
// R5 = R2 structure (P via LDS round-trip — R4's shfl transform put 8
// serialized ds_bpermute latencies on the critical path at ~1 block/CU
// residency and tripled time) + pack_bf2 cheap conversion + REGISTER
// PREFETCH double-buffer: tile kt+1's global loads are issued after the
// post-stage barrier so they overlap tile kt's compute. Barriers drain
// vmcnt exactly where the data is needed (top of next iteration).

typedef __bf16 bf16x8 __attribute__((ext_vector_type(8)));
typedef float f32x16 __attribute__((ext_vector_type(16)));
typedef unsigned short u16x8 __attribute__((ext_vector_type(8)));
typedef unsigned short u16x4 __attribute__((ext_vector_type(4)));
typedef unsigned int u32x2 __attribute__((ext_vector_type(2)));

#define T_SEQ 4096
#define D_HEAD 128
#define BQ 128          // q rows per block (4 waves x 32)
#define BK 64           // kv rows per tile
#define KSTR 136        // K_lds row stride in shorts (128 + 8 pad)
#define VSTR 72         // Vt_lds row stride in shorts (64 + 8 pad)
#define PSTR 72         // Pq row stride in shorts

// pack two f32 -> bf16x2 (round-half-up: +0x8000, take hi16). 3 VALU / 2 elem.
__device__ __forceinline__ unsigned int pack_bf2(float a, float b) {
    unsigned int ua = __builtin_bit_cast(unsigned int, a) + 0x8000u;
    unsigned int ub = __builtin_bit_cast(unsigned int, b) + 0x8000u;
    return __builtin_amdgcn_perm(ub, ua, 0x07060302);  // [ub.hi16 | ua.hi16]
}

__global__ __launch_bounds__(256, 2) void fa_fwd(
    const float* __restrict__ Qg, const float* __restrict__ Kg,
    const float* __restrict__ Vg, float* __restrict__ Og)
{
    __shared__ unsigned short K_lds[BK * KSTR];        // K[kv][d]     17408 B
    __shared__ unsigned short Vt_lds[D_HEAD * VSTR];   // V^T[d][kv]   18432 B
    __shared__ unsigned short Pq_lds[4 * 32 * PSTR];   // per-wave P[q][kv] 18432 B

    const int tid  = threadIdx.x;
    const int w    = tid >> 6;      // wave 0..3
    const int lane = tid & 63;
    const int r    = lane & 31;     // n-index within MFMA tiles
    const int h    = lane >> 5;     // half-wave

    const int qt = (int)(gridDim.x - 1 - blockIdx.x); // big tiles first
    const int bh = blockIdx.y;
    const int q0 = qt * BQ;

    const float* Qb = Qg + (size_t)bh * T_SEQ * D_HEAD;
    const float* Kb = Kg + (size_t)bh * T_SEQ * D_HEAD;
    const float* Vb = Vg + (size_t)bh * T_SEQ * D_HEAD;
    float*       Ob = Og + (size_t)bh * T_SEQ * D_HEAD;

    const int qw      = q0 + 32 * w;
    const int q_lane  = qw + r;
    const int qw_last = qw + 31;

    // ---- Q fragments (B-operand), pre-scaled by 1/sqrt(D)*log2(e)
    const float qscale = 0.08838834764831845f * 1.4426950408889634f;
    bf16x8 qf[8];
#pragma unroll
    for (int c = 0; c < 8; ++c) {
        const float* src = Qb + (size_t)q_lane * D_HEAD + c * 16 + h * 8;
        float4 f0 = *(const float4*)(src);
        float4 f1 = *(const float4*)(src + 4);
        unsigned int u0 = pack_bf2(f0.x * qscale, f0.y * qscale);
        unsigned int u1 = pack_bf2(f0.z * qscale, f0.w * qscale);
        unsigned int u2 = pack_bf2(f1.x * qscale, f1.y * qscale);
        unsigned int u3 = pack_bf2(f1.z * qscale, f1.w * qscale);
        u16x8 u = { (unsigned short)u0, (unsigned short)(u0 >> 16),
                    (unsigned short)u1, (unsigned short)(u1 >> 16),
                    (unsigned short)u2, (unsigned short)(u2 >> 16),
                    (unsigned short)u3, (unsigned short)(u3 >> 16) };
        qf[c] = __builtin_bit_cast(bf16x8, u);
    }

    f32x16 o[4];
#pragma unroll
    for (int mt = 0; mt < 4; ++mt) o[mt] = (f32x16)0.0f;
    float m_run = -1e30f, l_run = 0.0f;

    unsigned short* Pw = &Pq_lds[w * 32 * PSTR];

    // staging geometry
    const int krow = tid >> 5;            // 0..7
    const int kd0  = (tid & 31) * 4;
    const int vd   = tid & 127;
    const int vhh  = tid >> 7;            // 0,1

    // ---- prefetch registers (tile kt+1 in flight during compute of kt)
    float4 kpre[8];
    float  vpre[8][4];

    // preload tile 0
#pragma unroll
    for (int p = 0; p < 8; ++p)
        kpre[p] = *(const float4*)(Kb + (size_t)(p * 8 + krow) * D_HEAD + kd0);
#pragma unroll
    for (int p = 0; p < 8; ++p) {
        const int kv0 = p * 8 + vhh * 4;
        const float* vs = Vb + (size_t)kv0 * D_HEAD + vd;
        vpre[p][0] = vs[0];
        vpre[p][1] = vs[D_HEAD];
        vpre[p][2] = vs[2 * D_HEAD];
        vpre[p][3] = vs[3 * D_HEAD];
    }

    const int ntiles = 2 * qt + 2;
    for (int kt = 0; kt < ntiles; ++kt) {
        const int kbase = kt * BK;
        __syncthreads();   // prev compute done with LDS; drains prefetch vmcnt

        // ---- write prefetched tile into LDS (pack to bf16)
#pragma unroll
        for (int p = 0; p < 8; ++p) {
            u32x2 u;
            u[0] = pack_bf2(kpre[p].x, kpre[p].y);
            u[1] = pack_bf2(kpre[p].z, kpre[p].w);
            *(u32x2*)&K_lds[(p * 8 + krow) * KSTR + kd0] = u;
        }
#pragma unroll
        for (int p = 0; p < 8; ++p) {
            u32x2 u;
            u[0] = pack_bf2(vpre[p][0], vpre[p][1]);
            u[1] = pack_bf2(vpre[p][2], vpre[p][3]);
            *(u32x2*)&Vt_lds[vd * VSTR + p * 8 + vhh * 4] = u;
        }
        __syncthreads();

        // ---- issue next tile's global loads; they fly during compute below
        if (kt + 1 < ntiles) {
            const int nb = kbase + BK;
#pragma unroll
            for (int p = 0; p < 8; ++p)
                kpre[p] = *(const float4*)(Kb + (size_t)(nb + p * 8 + krow) * D_HEAD + kd0);
#pragma unroll
            for (int p = 0; p < 8; ++p) {
                const int kv0 = nb + p * 8 + vhh * 4;
                const float* vs = Vb + (size_t)kv0 * D_HEAD + vd;
                vpre[p][0] = vs[0];
                vpre[p][1] = vs[D_HEAD];
                vpre[p][2] = vs[2 * D_HEAD];
                vpre[p][3] = vs[3 * D_HEAD];
            }
        }

        if (kbase > qw_last) continue;   // wave-uniform; barriers stay aligned

        // ---- S^T = K * Q^T : two 32-kv m-tiles
        f32x16 s[2];
        s[0] = (f32x16)0.0f; s[1] = (f32x16)0.0f;
#pragma unroll
        for (int t = 0; t < 2; ++t) {
#pragma unroll
            for (int c = 0; c < 8; ++c) {
                u16x8 raw = *(const u16x8*)&K_lds[(t * 32 + r) * KSTR + c * 16 + h * 8];
                bf16x8 a = __builtin_bit_cast(bf16x8, raw);
                s[t] = __builtin_amdgcn_mfma_f32_32x32x16_bf16(a, qf[c], s[t], 0, 0, 0);
            }
        }

        // ---- causal mask (vs wave's FIRST q — R1 bug fixed)
        if (kbase + BK - 1 > qw) {
#pragma unroll
            for (int t = 0; t < 2; ++t)
#pragma unroll
                for (int g = 0; g < 16; ++g) {
                    int kv = kbase + t * 32 + (g & 3) + 8 * (g >> 2) + 4 * h;
                    if (kv > q_lane) s[t][g] = -1e30f;
                }
        }

        // ---- online softmax (per q = lane&31; combine two half-waves)
        float mloc = -1e30f;
#pragma unroll
        for (int t = 0; t < 2; ++t)
#pragma unroll
            for (int g = 0; g < 16; ++g) mloc = fmaxf(mloc, s[t][g]);
        mloc = fmaxf(mloc, __shfl_xor(mloc, 32, 64));
        const float m_new = fmaxf(m_run, mloc);
        const float alpha = __builtin_amdgcn_exp2f(m_run - m_new);
        float rsum = 0.0f;
#pragma unroll
        for (int t = 0; t < 2; ++t)
#pragma unroll
            for (int g = 0; g < 16; ++g) {
                float p = __builtin_amdgcn_exp2f(s[t][g] - m_new);
                s[t][g] = p;
                rsum += p;
            }
        rsum += __shfl_xor(rsum, 32, 64);
        l_run = l_run * alpha + rsum;
        m_run = m_new;
#pragma unroll
        for (int mt = 0; mt < 4; ++mt)
#pragma unroll
            for (int g = 0; g < 16; ++g) o[mt][g] *= alpha;

        // ---- P to LDS: Pq[q=r][kv] (batched b64 writes, one latency)
#pragma unroll
        for (int t = 0; t < 2; ++t)
#pragma unroll
            for (int g4 = 0; g4 < 4; ++g4) {
                unsigned int u0 = pack_bf2(s[t][g4 * 4 + 0], s[t][g4 * 4 + 1]);
                unsigned int u1 = pack_bf2(s[t][g4 * 4 + 2], s[t][g4 * 4 + 3]);
                u32x2 u; u[0] = u0; u[1] = u1;
                *(u32x2*)&Pw[r * PSTR + t * 32 + g4 * 8 + h * 4] = u;
            }

        // ---- P^T B-fragments (b128 reads), then O^T += V^T * P^T
        bf16x8 pf[4];
#pragma unroll
        for (int c = 0; c < 4; ++c) {
            u16x8 raw = *(const u16x8*)&Pw[r * PSTR + c * 16 + h * 8];
            pf[c] = __builtin_bit_cast(bf16x8, raw);
        }
#pragma unroll
        for (int mt = 0; mt < 4; ++mt) {
#pragma unroll
            for (int c = 0; c < 4; ++c) {
                u16x8 raw = *(const u16x8*)&Vt_lds[(mt * 32 + r) * VSTR + c * 16 + h * 8];
                bf16x8 a = __builtin_bit_cast(bf16x8, raw);
                o[mt] = __builtin_amdgcn_mfma_f32_32x32x16_bf16(a, pf[c], o[mt], 0, 0, 0);
            }
        }
    }

    // ---- epilogue: O[q][d] = O^T / l
    const float inv = 1.0f / l_run;
#pragma unroll
    for (int mt = 0; mt < 4; ++mt)
#pragma unroll
        for (int g4 = 0; g4 < 4; ++g4) {
            float4 vv;
            vv.x = o[mt][g4 * 4 + 0] * inv;
            vv.y = o[mt][g4 * 4 + 1] * inv;
            vv.z = o[mt][g4 * 4 + 2] * inv;
            vv.w = o[mt][g4 * 4 + 3] * inv;
            const int dd = mt * 32 + g4 * 8 + h * 4;
            *(float4*)(Ob + (size_t)q_lane * D_HEAD + dd) = vv;
        }
}

extern "C" void kernel_launch(void* const* d_in, const int* in_sizes, int n_in,
                              void* d_out, int out_size, void* d_ws, size_t ws_size,
                              hipStream_t stream) {
    const float* Q = (const float*)d_in[0];
    const float* K = (const float*)d_in[1];
    const float* V = (const float*)d_in[2];
    float* O = (float*)d_out;
    const int BH = in_sizes[0] / (T_SEQ * D_HEAD);   // 32
    dim3 grid(T_SEQ / BQ, BH, 1);
    fa_fwd<<<grid, 256, 0, stream>>>(Q, K, V, O);
}